// Round 1
// baseline (441.627 us; speedup 1.0000x reference)
//
#include <hip/hip_runtime.h>

#define N_TOK 262144
#define D_FEAT 128
#define C_CLS 64
#define TILE_M 256                      // rows per super-tile (8 waves x 32)
#define NBLOCKS 512
#define BLOCK_T 512                     // 8 waves per block
#define NTILES (N_TOK / TILE_M)         // 1024
#define TILES_PER_BLOCK (NTILES / NBLOCKS)  // 2

typedef __attribute__((ext_vector_type(8))) short bf16x8;
typedef __attribute__((ext_vector_type(4))) float f32x4;

__device__ __forceinline__ unsigned short f2bf(float x) {
    unsigned u = __float_as_uint(x);
    u += 0x7FFFu + ((u >> 16) & 1u);   // RTNE
    return (unsigned short)(u >> 16);
}

__device__ __forceinline__ bf16x8 pack8(float4 a, float4 b) {
    bf16x8 t;
    t[0] = (short)f2bf(a.x); t[1] = (short)f2bf(a.y);
    t[2] = (short)f2bf(a.z); t[3] = (short)f2bf(a.w);
    t[4] = (short)f2bf(b.x); t[5] = (short)f2bf(b.y);
    t[6] = (short)f2bf(b.z); t[7] = (short)f2bf(b.w);
    return t;
}

// Fused: distance GEMM (bf16 MFMA) + per-class segment sums + counts + loss gather.
// v2: 8-wave blocks (2x occupancy), no per-tile barrier (waves free-run),
//     label staged once per wave (LDS broadcast in the seg loop).
__global__ __launch_bounds__(BLOCK_T, 4) void center_main(
    const float* __restrict__ f, const int* __restrict__ label,
    const float* __restrict__ centers, float* __restrict__ dist_out,
    float* __restrict__ ws_loss, unsigned* __restrict__ ws_cnt,
    float* __restrict__ ws_seg)
{
    __shared__ float    seg[C_CLS * D_FEAT];   // 32 KB fp32 segment sums
    __shared__ float    c2s[C_CLS];
    __shared__ float    f2t[TILE_M];
    __shared__ int      lblt[TILE_M];
    __shared__ unsigned cnts[C_CLS];

    const int tid  = threadIdx.x;
    const int lane = tid & 63;
    const int w    = tid >> 6;        // wave id 0..7
    const int qk   = lane >> 4;       // k-quad 0..3
    const int ln   = lane & 15;

    // ---- block setup ----
    for (int i = tid; i < C_CLS * D_FEAT; i += BLOCK_T) seg[i] = 0.f;
    if (tid < C_CLS) {
        cnts[tid] = 0u;
        float s = 0.f;
        const float* cp = centers + tid * D_FEAT;
        for (int k = 0; k < D_FEAT; k += 4) {
            float4 v = *(const float4*)(cp + k);
            s += v.x*v.x + v.y*v.y + v.z*v.z + v.w*v.w;
        }
        c2s[tid] = s;
    }

    // B fragments (centers as bf16), held in registers for the whole kernel.
    // B[k][n]: lane holds n = ln, k = ks*32 + qk*8 + j
    bf16x8 bfr[4][4];
    #pragma unroll
    for (int ct = 0; ct < 4; ++ct) {
        const float* bp = centers + (ct * 16 + ln) * D_FEAT + qk * 8;
        #pragma unroll
        for (int ks = 0; ks < 4; ++ks) {
            float4 v0 = *(const float4*)(bp + ks * 32);
            float4 v1 = *(const float4*)(bp + ks * 32 + 4);
            bfr[ct][ks] = pack8(v0, v1);
        }
    }
    __syncthreads();   // seg zero + c2s ready

    float lossa = 0.f;

    for (int s = 0; s < TILES_PER_BLOCK; ++s) {
        const int tile = blockIdx.x + s * NBLOCKS;
        const int base = tile * TILE_M;
        const int row0 = base + w * 32;        // this wave's 32 rows

        // ---- labels: one coalesced load per wave, staged to LDS ----
        if (lane < 32) {
            const int lv = label[row0 + lane];
            lblt[w * 32 + lane] = lv;
            atomicAdd(&cnts[lv], 1u);
        }

        // ---- pass 1a: segment sums (wave owns rows row0..row0+31) ----
        #pragma unroll 8
        for (int rr = 0; rr < 32; ++rr) {
            const int lb = lblt[w * 32 + rr];   // same-address LDS broadcast
            const int rg = row0 + rr;
            const float a = f[(size_t)rg * D_FEAT + lane];
            const float b = f[(size_t)rg * D_FEAT + 64 + lane];
            atomicAdd(&seg[lb * D_FEAT + lane], a);        // bank = lane&31 -> 2-way, free
            atomicAdd(&seg[lb * D_FEAT + 64 + lane], b);
        }

        // ---- pass 1b: f2 per row (2 threads per row, data is L1/L2-hot) ----
        {
            const int rl   = tid >> 1;     // 0..255 (wave w covers its own rows 32w..32w+31)
            const int half = tid & 1;
            const float* rp = f + (size_t)(base + rl) * D_FEAT + half * 64;
            float s2 = 0.f;
            #pragma unroll
            for (int j = 0; j < 64; j += 4) {
                float4 v = *(const float4*)(rp + j);
                s2 += v.x*v.x + v.y*v.y + v.z*v.z + v.w*v.w;
            }
            s2 += __shfl_xor(s2, 1);
            if (half == 0) f2t[rl] = s2;
        }
        // No barrier: every wave only reads f2t/lblt rows it wrote itself,
        // seg/cnts are atomic-only until the final flush barrier.

        // ---- pass 2: MFMA GEMM tile + epilogue ----
        #pragma unroll
        for (int rt = 0; rt < 2; ++rt) {
            const int rbase = base + w * 32 + rt * 16;
            // A frags: lane holds m = ln, k = ks*32 + qk*8 + j  (L1/L2-hot)
            bf16x8 afr[4];
            const float* ap = f + (size_t)(rbase + ln) * D_FEAT + qk * 8;
            #pragma unroll
            for (int ks = 0; ks < 4; ++ks) {
                float4 v0 = *(const float4*)(ap + ks * 32);
                float4 v1 = *(const float4*)(ap + ks * 32 + 4);
                afr[ks] = pack8(v0, v1);
            }
            const int mloc = w * 32 + rt * 16 + qk * 4;  // this lane's 4 output rows (local)
            #pragma unroll
            for (int ct = 0; ct < 4; ++ct) {
                f32x4 acc = {0.f, 0.f, 0.f, 0.f};
                #pragma unroll
                for (int ks = 0; ks < 4; ++ks)
                    acc = __builtin_amdgcn_mfma_f32_16x16x32_bf16(
                        afr[ks], bfr[ct][ks], acc, 0, 0, 0);
                const int n    = ct * 16 + ln;
                const float cv = c2s[n];
                float* op = dist_out + (size_t)(rbase + qk * 4) * C_CLS + n;
                #pragma unroll
                for (int v = 0; v < 4; ++v) {
                    const float dv = f2t[mloc + v] + cv - 2.f * acc[v];
                    op[(size_t)v * C_CLS] = dv;
                    if (lblt[mloc + v] == n) lossa += dv;   // dist[i][lbl_i] = ||f_i-c_lbl||^2
                }
            }
        }
        // no per-tile barrier
    }

    // ---- flush block partials ----
    __syncthreads();   // all waves' seg/cnts atomics complete
    for (int i = tid; i < C_CLS * D_FEAT; i += BLOCK_T)
        unsafeAtomicAdd(&ws_seg[i], seg[i]);
    if (tid < C_CLS) atomicAdd(&ws_cnt[tid], cnts[tid]);
    #pragma unroll
    for (int off = 32; off; off >>= 1) lossa += __shfl_xor(lossa, off);
    if (lane == 0) unsafeAtomicAdd(ws_loss, lossa);
}

__global__ void center_fin(const float* __restrict__ centers,
                           const float* __restrict__ ws_loss,
                           const unsigned* __restrict__ ws_cnt,
                           const float* __restrict__ ws_seg,
                           float* __restrict__ out)
{
    const int i = blockIdx.x * 256 + threadIdx.x;
    if (i == 0) out[0] = ws_loss[0] / ((float)N_TOK * (float)D_FEAT);
    if (i < C_CLS * D_FEAT) {
        const int c = i >> 7;
        const unsigned cnt = ws_cnt[c];
        const float denom = (float)(cnt > 1u ? cnt : 1u);
        out[1 + i] = ((float)cnt * centers[i] - ws_seg[i]) / denom;
    }
}

extern "C" void kernel_launch(void* const* d_in, const int* in_sizes, int n_in,
                              void* d_out, int out_size, void* d_ws, size_t ws_size,
                              hipStream_t stream)
{
    const float* f       = (const float*)d_in[0];
    const int*   lbl     = (const int*)d_in[1];
    const float* centers = (const float*)d_in[2];
    float* out = (float*)d_out;

    float*    ws_loss = (float*)d_ws;
    unsigned* ws_cnt  = (unsigned*)((char*)d_ws + 256);
    float*    ws_seg  = (float*)((char*)d_ws + 1024);

    // zero the accumulators (ws is poisoned 0xAA before every timed launch)
    hipMemsetAsync(d_ws, 0, 1024 + C_CLS * D_FEAT * sizeof(float), stream);

    float* dist_out = out + 1 + C_CLS * D_FEAT;
    center_main<<<NBLOCKS, BLOCK_T, 0, stream>>>(f, lbl, centers, dist_out,
                                                 ws_loss, ws_cnt, ws_seg);
    center_fin<<<32, 256, 0, stream>>>(centers, ws_loss, ws_cnt, ws_seg, out);
}

// Round 2
// 375.874 us; speedup vs baseline: 1.1749x; 1.1749x over previous
//
#include <hip/hip_runtime.h>

#define N_TOK 262144
#define D_FEAT 128
#define C_CLS 64
#define TILE_M 128                       // rows per tile (4 waves x 32)
#define NBLOCKS 1024
#define BLOCK_T 256
#define NTILES (N_TOK / TILE_M)          // 2048
#define TILES_PER_BLOCK (NTILES / NBLOCKS)  // 2

typedef __attribute__((ext_vector_type(8))) short bf16x8;
typedef __attribute__((ext_vector_type(4))) float f32x4;

__device__ __forceinline__ unsigned short f2bf(float x) {
    unsigned u = __float_as_uint(x);
    u += 0x7FFFu + ((u >> 16) & 1u);   // RTNE
    return (unsigned short)(u >> 16);
}

__device__ __forceinline__ bf16x8 pack8(float4 a, float4 b) {
    bf16x8 t;
    t[0] = (short)f2bf(a.x); t[1] = (short)f2bf(a.y);
    t[2] = (short)f2bf(a.z); t[3] = (short)f2bf(a.w);
    t[4] = (short)f2bf(b.x); t[5] = (short)f2bf(b.y);
    t[6] = (short)f2bf(b.z); t[7] = (short)f2bf(b.w);
    return t;
}

// v3: SINGLE-PASS over f. Each f element is loaded from global exactly once
// (into the MFMA A-fragment registers); f2, seg-sums and bf16 frags are all
// derived from those registers. Seg atomics use a label-XOR bank swizzle
// (fragment layout would otherwise be a 16-way conflict).
__global__ __launch_bounds__(BLOCK_T, 3) void center_main(
    const float* __restrict__ f, const int* __restrict__ label,
    const float* __restrict__ centers, float* __restrict__ dist_out,
    float* __restrict__ ws_loss, unsigned* __restrict__ ws_cnt,
    float* __restrict__ ws_seg)
{
    __shared__ float    seg[C_CLS * D_FEAT];   // 32 KB fp32, col XOR-swizzled by (class&31)
    __shared__ float    c2s[C_CLS];
    __shared__ float    f2t[TILE_M];
    __shared__ int      lblt[TILE_M];
    __shared__ unsigned cnts[C_CLS];

    const int tid  = threadIdx.x;
    const int lane = tid & 63;
    const int w    = tid >> 6;        // wave id 0..3
    const int qk   = lane >> 4;       // k-quad 0..3
    const int ln   = lane & 15;

    // ---- block setup ----
    for (int i = tid; i < C_CLS * D_FEAT; i += BLOCK_T) seg[i] = 0.f;
    if (tid < C_CLS) {
        cnts[tid] = 0u;
        float s = 0.f;
        const float* cp = centers + tid * D_FEAT;
        for (int k = 0; k < D_FEAT; k += 4) {
            float4 v = *(const float4*)(cp + k);
            s += v.x*v.x + v.y*v.y + v.z*v.z + v.w*v.w;
        }
        c2s[tid] = s;
    }

    // B fragments (centers as bf16), in registers for the whole kernel.
    // B[k][n]: lane holds n = ln, k = ks*32 + qk*8 + j
    bf16x8 bfr[4][4];
    #pragma unroll
    for (int ct = 0; ct < 4; ++ct) {
        const float* bp = centers + (ct * 16 + ln) * D_FEAT + qk * 8;
        #pragma unroll
        for (int ks = 0; ks < 4; ++ks) {
            float4 v0 = *(const float4*)(bp + ks * 32);
            float4 v1 = *(const float4*)(bp + ks * 32 + 4);
            bfr[ct][ks] = pack8(v0, v1);
        }
    }
    __syncthreads();   // seg zero + c2s ready

    float lossa = 0.f;

    for (int s = 0; s < TILES_PER_BLOCK; ++s) {
        const int tile = blockIdx.x + s * NBLOCKS;
        const int base = tile * TILE_M;
        const int row0 = base + w * 32;        // this wave's 32 rows

        // labels: one coalesced load per wave, staged to LDS (wave-private rows)
        if (lane < 32) {
            const int lv = label[row0 + lane];
            lblt[w * 32 + lane] = lv;
            atomicAdd(&cnts[lv], 1u);
        }

        #pragma unroll
        for (int rt = 0; rt < 2; ++rt) {
            const int rbase = row0 + rt * 16;
            // The ONLY read of these 16 rows: lane (qk,ln) loads row rbase+ln,
            // cols qk*8 + ks*32 + {0..7}  (8 x float4 = 32 floats/lane)
            const float* ap = f + (size_t)(rbase + ln) * D_FEAT + qk * 8;
            float4 v[8];
            #pragma unroll
            for (int ks = 0; ks < 4; ++ks) {
                v[2*ks]   = *(const float4*)(ap + ks * 32);
                v[2*ks+1] = *(const float4*)(ap + ks * 32 + 4);
            }

            // f2 from registers: lane partial, then reduce across the 4 qk-groups
            float s2 = 0.f;
            #pragma unroll
            for (int i = 0; i < 8; ++i)
                s2 += v[i].x*v[i].x + v[i].y*v[i].y + v[i].z*v[i].z + v[i].w*v[i].w;
            s2 += __shfl_xor(s2, 16);
            s2 += __shfl_xor(s2, 32);
            if (lane < 16) f2t[w * 32 + rt * 16 + lane] = s2;   // lane==ln, row rbase+ln

            // A fragments (bf16) from the same registers
            bf16x8 afr[4];
            #pragma unroll
            for (int ks = 0; ks < 4; ++ks) afr[ks] = pack8(v[2*ks], v[2*ks+1]);

            // seg atomics from registers. Col swizzled by (lb&31): for a fixed
            // (ks,j) instruction the 16 ln-lanes land in distinct banks unless
            // labels collide. Unswizzled at flush.
            {
                const int lb = lblt[w * 32 + rt * 16 + ln];
                const int sw = lb & 31;
                const int cb = (lb << 7);
                const float* vf = (const float*)v;
                #pragma unroll
                for (int ks = 0; ks < 4; ++ks) {
                    #pragma unroll
                    for (int j = 0; j < 8; ++j) {
                        const int col = ks * 32 + qk * 8 + j;
                        atomicAdd(&seg[cb + (col ^ sw)], vf[ks * 8 + j]);
                    }
                }
            }

            // MFMA + epilogue
            const int mloc = w * 32 + rt * 16 + qk * 4;
            #pragma unroll
            for (int ct = 0; ct < 4; ++ct) {
                f32x4 acc = {0.f, 0.f, 0.f, 0.f};
                #pragma unroll
                for (int ks = 0; ks < 4; ++ks)
                    acc = __builtin_amdgcn_mfma_f32_16x16x32_bf16(
                        afr[ks], bfr[ct][ks], acc, 0, 0, 0);
                const int n    = ct * 16 + ln;
                const float cv = c2s[n];
                float* op = dist_out + (size_t)(rbase + qk * 4) * C_CLS + n;
                #pragma unroll
                for (int v4 = 0; v4 < 4; ++v4) {
                    const float dv = f2t[mloc + v4] + cv - 2.f * acc[v4];
                    op[(size_t)v4 * C_CLS] = dv;
                    if (lblt[mloc + v4] == n) lossa += dv;
                }
            }
        }
        // no per-tile barrier: f2t/lblt are wave-private, seg/cnts atomic-only
    }

    // ---- flush block partials (unswizzle seg) ----
    __syncthreads();
    for (int i = tid; i < C_CLS * D_FEAT; i += BLOCK_T) {
        const int c   = i >> 7;
        const int col = i & 127;
        unsafeAtomicAdd(&ws_seg[i], seg[(c << 7) + (col ^ (c & 31))]);
    }
    if (tid < C_CLS) atomicAdd(&ws_cnt[tid], cnts[tid]);
    #pragma unroll
    for (int off = 32; off; off >>= 1) lossa += __shfl_xor(lossa, off);
    if (lane == 0) unsafeAtomicAdd(ws_loss, lossa);
}

__global__ void center_fin(const float* __restrict__ centers,
                           const float* __restrict__ ws_loss,
                           const unsigned* __restrict__ ws_cnt,
                           const float* __restrict__ ws_seg,
                           float* __restrict__ out)
{
    const int i = blockIdx.x * 256 + threadIdx.x;
    if (i == 0) out[0] = ws_loss[0] / ((float)N_TOK * (float)D_FEAT);
    if (i < C_CLS * D_FEAT) {
        const int c = i >> 7;
        const unsigned cnt = ws_cnt[c];
        const float denom = (float)(cnt > 1u ? cnt : 1u);
        out[1 + i] = ((float)cnt * centers[i] - ws_seg[i]) / denom;
    }
}

extern "C" void kernel_launch(void* const* d_in, const int* in_sizes, int n_in,
                              void* d_out, int out_size, void* d_ws, size_t ws_size,
                              hipStream_t stream)
{
    const float* f       = (const float*)d_in[0];
    const int*   lbl     = (const int*)d_in[1];
    const float* centers = (const float*)d_in[2];
    float* out = (float*)d_out;

    float*    ws_loss = (float*)d_ws;
    unsigned* ws_cnt  = (unsigned*)((char*)d_ws + 256);
    float*    ws_seg  = (float*)((char*)d_ws + 1024);

    // zero the accumulators (ws is poisoned 0xAA before every timed launch)
    hipMemsetAsync(d_ws, 0, 1024 + C_CLS * D_FEAT * sizeof(float), stream);

    float* dist_out = out + 1 + C_CLS * D_FEAT;
    center_main<<<NBLOCKS, BLOCK_T, 0, stream>>>(f, lbl, centers, dist_out,
                                                 ws_loss, ws_cnt, ws_seg);
    center_fin<<<32, 256, 0, stream>>>(centers, ws_loss, ws_cnt, ws_seg, out);
}